// Round 16
// baseline (218.134 us; speedup 1.0000x reference)
//
#include <hip/hip_runtime.h>
#include <hip/hip_bf16.h>

#define B_ 4
#define S_ 128
#define D_ 512
#define H_ 8
#define DH_ 64
#define F_ 2048
#define R_ 8
#define BS_ (B_ * S_)
#define BSD_ (BS_ * D_)
#define E_ 262144          // 512*512

typedef __attribute__((ext_vector_type(8))) short short8;
typedef __attribute__((ext_vector_type(4))) float f32x4;
typedef __attribute__((ext_vector_type(4))) unsigned short ushort4v;

// fp32 -> bf16 hi (RNE) + bf16 lo (RNE of exact residual)
__device__ __forceinline__ void split2(float a, unsigned short& h, unsigned short& l) {
    unsigned u = __float_as_uint(a);
    unsigned hr = (u + 0x7FFFu + ((u >> 16) & 1u)) >> 16;
    h = (unsigned short)hr;
    float lo = a - __uint_as_float(hr << 16);
    unsigned u2 = __float_as_uint(lo);
    l = (unsigned short)((u2 + 0x7FFFu + ((u2 >> 16) & 1u)) >> 16);
}

// ---------------- prep: weight transpose+split (blocks < nt) + LN1 (rest) ----------------
struct TDesc { const float* s; unsigned short* h; unsigned short* l; int K; int N; int off; };
struct TPack { TDesc d[10]; };

__global__ void prep_kernel(TPack p, int nt, const float* __restrict__ x,
                            const float* __restrict__ g, const float* __restrict__ be,
                            unsigned short* __restrict__ xh, unsigned short* __restrict__ xl) {
    __shared__ float tr[32][33];
    __shared__ float red[256];
    int bid = blockIdx.x;
    if (bid < nt) {
        int wi = 0;
#pragma unroll
        for (int i = 1; i < 10; ++i) if (bid >= p.d[i].off) wi = i;
        const TDesc dd = p.d[wi];
        int t = bid - dd.off;
        int ntk = dd.K / 32;
        int tk = t % ntk, tn = t / ntk;
        int k0 = tk * 32, n0 = tn * 32;
        int col = threadIdx.x & 31, rg = threadIdx.x >> 5;   // rg 0..7
#pragma unroll
        for (int i = 0; i < 4; ++i) {
            int row = rg * 4 + i;
            tr[row][col] = dd.s[(size_t)(k0 + row) * dd.N + n0 + col];
        }
        __syncthreads();
#pragma unroll
        for (int i = 0; i < 4; ++i) {
            int n = n0 + rg * 4 + i;
            int k = k0 + col;
            unsigned short h, l;
            split2(tr[col][rg * 4 + i], h, l);
            dd.h[(size_t)n * dd.K + k] = h;
            dd.l[(size_t)n * dd.K + k] = l;
        }
    } else {
        int row = bid - nt;
        int t = threadIdx.x;
        const float* xr = x + (size_t)row * D_;
        float v0 = xr[t], v1 = xr[t + 256];
        red[t] = v0 + v1;
        __syncthreads();
        for (int off = 128; off > 0; off >>= 1) { if (t < off) red[t] += red[t + off]; __syncthreads(); }
        float mean = red[0] * (1.0f / D_);
        __syncthreads();
        float d0 = v0 - mean, d1 = v1 - mean;
        red[t] = d0 * d0 + d1 * d1;
        __syncthreads();
        for (int off = 128; off > 0; off >>= 1) { if (t < off) red[t] += red[t + off]; __syncthreads(); }
        float rs = rsqrtf(red[0] * (1.0f / D_) + 1e-5f);
        float o0 = d0 * rs * g[t] + be[t];
        float o1 = d1 * rs * g[t + 256] + be[t + 256];
        unsigned short h, l;
        split2(o0, h, l); xh[(size_t)row * D_ + t] = h;       xl[(size_t)row * D_ + t] = l;
        split2(o1, h, l); xh[(size_t)row * D_ + t + 256] = h; xl[(size_t)row * D_ + t + 256] = l;
    }
}

// ---------------- MFMA bf16x3 GEMM core: BK=64, 4-buf 3-deep DMA pipeline, ONE barrier/step ----------------
// XOR swizzle (both-sides, rule21): linear DMA dest; SOURCE chunk ^= (row&7); READ chunk ^= (row&7).
// Invariants: (1) a wave reaches step-s's barrier only after finishing step-(s-1)'s LDS reads, so
// restaging buf (s+3)%4 (last read at step s-1) AFTER the barrier cannot race any reader.
// (2) vmcnt: outstanding entering step s = {s, s+1, s+2} -> vmcnt(16) retires batch s exactly;
// batches s+1, s+2 stay in flight with two full MFMA phases of slack. MFMA order unchanged.
struct GemmLds {
    unsigned short A[4][2][64][64];    // [buf][hi/lo][row][k]  (8192 ushorts per buf)
    unsigned short B[4][2][64][64];
};                                     // 131072 bytes (1 block/CU; all grids >= 256 blocks)

__device__ __forceinline__ void gload16(const unsigned short* g, unsigned short* l) {
    __builtin_amdgcn_global_load_lds(
        (const __attribute__((address_space(1))) void*)g,
        (__attribute__((address_space(3))) void*)l, 16, 0, 0);
}

__device__ __forceinline__ void mgemm_core(const unsigned short* __restrict__ Ath,
                                           const unsigned short* __restrict__ Atl,
                                           const unsigned short* __restrict__ Bth,
                                           const unsigned short* __restrict__ Btl,
                                           int K, int rowBase, int colBase,
                                           int kStart, int nsteps,   // nsteps = kLen/64
                                           f32x4 acc[2][2], GemmLds* L) {
    int tid = threadIdx.x;
    int w = tid >> 6, lane = tid & 63;
    int lm = lane & 15, quad = lane >> 4;
    int wm = (w & 1) * 32, wn = (w >> 1) * 32;
    int r0 = w * 8 + (lane >> 3);                 // staged row (half 0); half 1 = +32
    int lc = ((lane & 7) ^ (lane >> 3)) * 8;      // swizzled source col (involution)
    int wb = w * 512;                             // wave's ushort offset within 4096B half
    size_t a0 = (size_t)(rowBase + r0) * K + kStart + lc;
    size_t a1 = (size_t)(rowBase + r0 + 32) * K + kStart + lc;
    size_t b0 = (size_t)(colBase + r0) * K + kStart + lc;
    size_t b1 = (size_t)(colBase + r0 + 32) * K + kStart + lc;
    unsigned short* AB = &L->A[0][0][0][0];
    unsigned short* BB = &L->B[0][0][0][0];
    auto stage = [&](int buf, size_t koff) {      // 8 vmem ops per call
        gload16(&Ath[a0 + koff], AB + buf * 8192 + wb);
        gload16(&Ath[a1 + koff], AB + buf * 8192 + 2048 + wb);
        gload16(&Atl[a0 + koff], AB + buf * 8192 + 4096 + wb);
        gload16(&Atl[a1 + koff], AB + buf * 8192 + 6144 + wb);
        gload16(&Bth[b0 + koff], BB + buf * 8192 + wb);
        gload16(&Bth[b1 + koff], BB + buf * 8192 + 2048 + wb);
        gload16(&Btl[b0 + koff], BB + buf * 8192 + 4096 + wb);
        gload16(&Btl[b1 + koff], BB + buf * 8192 + 6144 + wb);
    };
    // prologue: 3 batches in flight
    stage(0, 0);
    if (nsteps > 1) stage(1, 64);
    if (nsteps > 2) stage(2, 128);
    for (int s = 0; s < nsteps; ++s) {
        int b = s & 3;
        int remain = nsteps - 1 - s;              // batches still in flight beyond s
        if (remain >= 2)      asm volatile("s_waitcnt vmcnt(16)" ::: "memory");
        else if (remain == 1) asm volatile("s_waitcnt vmcnt(8)" ::: "memory");
        else                  asm volatile("s_waitcnt vmcnt(0)" ::: "memory");
        __builtin_amdgcn_s_barrier();             // all waves' buf-b DMA landed
        __builtin_amdgcn_sched_barrier(0);
        if (s + 3 < nsteps) stage((s + 3) & 3, (size_t)(s + 3) * 64);  // overlaps reads+MFMA
#pragma unroll
        for (int sub = 0; sub < 2; ++sub) {
            short8 ah[2], al[2], bh[2], bl[2];
            int pc = ((sub * 4 + quad) ^ (lm & 7)) * 8;          // swizzled read chunk
#pragma unroll
            for (int t = 0; t < 2; ++t) {
                int ra = (wm + t * 16 + lm) * 64 + pc;
                int rb = (wn + t * 16 + lm) * 64 + pc;
                ah[t] = *(const short8*)(AB + b * 8192 + ra);
                al[t] = *(const short8*)(AB + b * 8192 + 4096 + ra);
                bh[t] = *(const short8*)(BB + b * 8192 + rb);
                bl[t] = *(const short8*)(BB + b * 8192 + 4096 + rb);
            }
#pragma unroll
            for (int tm = 0; tm < 2; ++tm)
#pragma unroll
                for (int tn = 0; tn < 2; ++tn) {
                    acc[tm][tn] = __builtin_amdgcn_mfma_f32_16x16x32_bf16(ah[tm], bh[tn], acc[tm][tn], 0, 0, 0);
                    acc[tm][tn] = __builtin_amdgcn_mfma_f32_16x16x32_bf16(ah[tm], bl[tn], acc[tm][tn], 0, 0, 0);
                    acc[tm][tn] = __builtin_amdgcn_mfma_f32_16x16x32_bf16(al[tm], bh[tn], acc[tm][tn], 0, 0, 0);
                }
        }
        __builtin_amdgcn_sched_barrier(0);
    }
}

__device__ __forceinline__ void gemm_epilogue(f32x4 acc[2][2], const float* bias,
                                              float* Cf, unsigned short* Ch, unsigned short* Cl,
                                              int N, int relu, int rowBase, int colBase) {
    int tid = threadIdx.x;
    int w = tid >> 6, lane = tid & 63;
    int lm = lane & 15, quad = lane >> 4;
    int wm = (w & 1) * 32, wn = (w >> 1) * 32;
#pragma unroll
    for (int tm = 0; tm < 2; ++tm)
#pragma unroll
        for (int tn = 0; tn < 2; ++tn) {
            int col = colBase + wn + tn * 16 + lm;
            float bi = bias ? bias[col] : 0.f;
#pragma unroll
            for (int r = 0; r < 4; ++r) {
                int row = rowBase + wm + tm * 16 + quad * 4 + r;
                float v = acc[tm][tn][r] + bi;
                if (relu) v = fmaxf(v, 0.f);
                size_t o = (size_t)row * N + col;
                if (Cf) Cf[o] = v;
                if (Ch) {
                    unsigned short sh, sl;
                    split2(v, sh, sl);
                    Ch[o] = sh; Cl[o] = sl;
                }
            }
        }
}

// Generic GEMM: optional fp32 out, optional pre-split bf16 h/l out.
__global__ __launch_bounds__(256) void mgemm_kernel(const unsigned short* __restrict__ Ath,
                                                    const unsigned short* __restrict__ Atl,
                                                    const unsigned short* __restrict__ Bth,
                                                    const unsigned short* __restrict__ Btl,
                                                    const float* __restrict__ bias,
                                                    float* __restrict__ Cf,
                                                    unsigned short* __restrict__ Ch,
                                                    unsigned short* __restrict__ Cl,
                                                    int N, int K, int relu) {
    __shared__ GemmLds L;
    int rowBase = blockIdx.y * 64, colBase = blockIdx.x * 64;
    f32x4 acc[2][2] = {};
    mgemm_core(Ath, Atl, Bth, Btl, K, rowBase, colBase, 0, K / 64, acc, &L);
    gemm_epilogue(acc, bias, Cf, Ch, Cl, N, relu, rowBase, colBase);
}

// z-batched GEMM over weight slabs (QKV: 3, rc halves: 2); fp32 out only.
__global__ __launch_bounds__(256) void mgemm_zw_kernel(const unsigned short* __restrict__ Ath,
                                                       const unsigned short* __restrict__ Atl,
                                                       const unsigned short* __restrict__ Bth,
                                                       const unsigned short* __restrict__ Btl,
                                                       const float* __restrict__ b0,
                                                       const float* __restrict__ b1,
                                                       const float* __restrict__ b2,
                                                       float* __restrict__ Cbase,
                                                       int M, int N, int K) {
    __shared__ GemmLds L;
    int z = blockIdx.z;
    const unsigned short* bth = Bth + (size_t)z * K * N;
    const unsigned short* btl = Btl + (size_t)z * K * N;
    const float* bias = (z == 0) ? b0 : (z == 1) ? b1 : b2;
    float* C = Cbase + (size_t)z * M * N;
    int rowBase = blockIdx.y * 64, colBase = blockIdx.x * 64;
    f32x4 acc[2][2] = {};
    mgemm_core(Ath, Atl, bth, btl, K, rowBase, colBase, 0, K / 64, acc, &L);
    gemm_epilogue(acc, bias, C, nullptr, nullptr, N, 0, rowBase, colBase);
}

// split-K partial GEMM: each z-slice writes its own fp32 slab (no atomics).
__global__ __launch_bounds__(256) void mgemm_part_kernel(const unsigned short* __restrict__ Ath,
                                                         const unsigned short* __restrict__ Atl,
                                                         const unsigned short* __restrict__ Bth,
                                                         const unsigned short* __restrict__ Btl,
                                                         float* __restrict__ Cbase,
                                                         int M, int N, int K) {
    __shared__ GemmLds L;
    int ks = gridDim.z, z = blockIdx.z;
    int kLen = K / ks, kStart = z * kLen;
    float* C = Cbase + (size_t)z * M * N;
    int rowBase = blockIdx.y * 64, colBase = blockIdx.x * 64;
    f32x4 acc[2][2] = {};
    mgemm_core(Ath, Atl, Bth, Btl, K, rowBase, colBase, kStart, kLen / 64, acc, &L);
    gemm_epilogue(acc, nullptr, C, nullptr, nullptr, N, 0, rowBase, colBase);
}

// wo GEMM (blocks 0..63) + adjacency bitmask via ballot (blocks 64..319)
__global__ __launch_bounds__(256) void wo_adj_kernel(const unsigned short* __restrict__ Ath,
                                                     const unsigned short* __restrict__ Atl,
                                                     const unsigned short* __restrict__ Bth,
                                                     const unsigned short* __restrict__ Btl,
                                                     const float* __restrict__ bias,
                                                     unsigned short* __restrict__ Ch,
                                                     unsigned short* __restrict__ Cl,
                                                     const float* __restrict__ attnP,
                                                     unsigned long long* __restrict__ adjm) {
    __shared__ GemmLds L;
    int bid = blockIdx.x;
    if (bid < 64) {
        int rowBase = (bid >> 3) * 64, colBase = (bid & 7) * 64;
        f32x4 acc[2][2] = {};
        mgemm_core(Ath, Atl, Bth, Btl, D_, rowBase, colBase, 0, D_ / 64, acc, &L);
        gemm_epilogue(acc, bias, nullptr, Ch, Cl, D_, 0, rowBase, colBase);
    } else {
        int idx = (bid - 64) * 256 + threadIdx.x;   // (b*S + i)*S + j
        int j = idx & (S_ - 1);
        int bi = idx >> 7;                           // row = b*S + i
        int i = bi & (S_ - 1);
        int b = bi >> 7;
        float s = 0.f;
#pragma unroll
        for (int h = 0; h < H_; ++h) s += attnP[(((size_t)(b * H_ + h)) * S_ + i) * S_ + j];
        s *= (1.0f / H_);
        int pred = (s > 0.1f && i != j) ? 1 : 0;
        unsigned long long m = __ballot(pred);
        if ((threadIdx.x & 63) == 0)
            adjm[(size_t)bi * 2 + ((threadIdx.x >> 6) & 1)] = m;
    }
}

// sum 4 partials + bias -> nu fp32 + bf16 h/l
__global__ void reduce4_kernel(const float* __restrict__ part, const float* __restrict__ b2,
                               float* __restrict__ nu,
                               unsigned short* __restrict__ nh, unsigned short* __restrict__ nl) {
    int base = blockIdx.x * 1024 + threadIdx.x * 4;
    f32x4 s = *(const f32x4*)&b2[base & (D_ - 1)];
#pragma unroll
    for (int z = 0; z < 4; ++z) s += *(const f32x4*)&part[(size_t)z * BSD_ + base];
    *(f32x4*)&nu[base] = s;
    ushort4v hv, lv;
#pragma unroll
    for (int i = 0; i < 4; ++i) { unsigned short h, l; split2(s[i], h, l); hv[i] = h; lv[i] = l; }
    *(ushort4v*)&nh[base] = hv;
    *(ushort4v*)&nl[base] = lv;
}

// reasoned = nu + sum 8 partials -> bf16 h/l only
__global__ void reduce8_kernel(const float* __restrict__ part, const float* __restrict__ nu,
                               unsigned short* __restrict__ rh, unsigned short* __restrict__ rl) {
    int base = blockIdx.x * 1024 + threadIdx.x * 4;
    f32x4 s = *(const f32x4*)&nu[base];
#pragma unroll
    for (int z = 0; z < 8; ++z) s += *(const f32x4*)&part[(size_t)z * BSD_ + base];
    ushort4v hv, lv;
#pragma unroll
    for (int i = 0; i < 4; ++i) { unsigned short h, l; split2(s[i], h, l); hv[i] = h; lv[i] = l; }
    *(ushort4v*)&rh[base] = hv;
    *(ushort4v*)&rl[base] = lv;
}

// ---------------- Attention v2: block = (b,h,16 i's); K tile LDS-staged, conflict-free dot ----------------
__global__ __launch_bounds__(512) void attn_kernel2(const float* __restrict__ q,
                                                    const float* __restrict__ k,
                                                    const float* __restrict__ v,
                                                    float* __restrict__ attnP,
                                                    unsigned short* __restrict__ ch,
                                                    unsigned short* __restrict__ cl) {
    __shared__ float ksm[S_][DH_ + 3];   // [128][67]
    __shared__ float qsm[16][DH_];
    __shared__ float psm[16][S_];
    int tid = threadIdx.x;
    int w = tid >> 6, lane = tid & 63;
    int blk = blockIdx.x;                // ((b*H + h)*8 + ig)
    int ig = blk & 7;
    int bh = blk >> 3;
    int h = bh & (H_ - 1);
    int b = bh >> 3;
    int i0 = ig * 16;
    const float* kb = k + (size_t)b * S_ * D_ + h * DH_;
    for (int j = w; j < S_; j += 8) ksm[j][lane] = kb[(size_t)j * D_ + lane];
    for (int il = w; il < 16; il += 8)
        qsm[il][lane] = q[(size_t)(b * S_ + i0 + il) * D_ + h * DH_ + lane];
    __syncthreads();
    const float* vb = v + (size_t)b * S_ * D_ + h * DH_ + lane;
#pragma unroll
    for (int c = 0; c < 2; ++c) {
        int il = w + c * 8;
        int i = i0 + il;
        float s0 = 0.f, s1 = 0.f;
#pragma unroll 8
        for (int d = 0; d < DH_; ++d) {
            float qd = qsm[il][d];
            s0 += qd * ksm[lane][d];
            s1 += qd * ksm[lane + 64][d];
        }
        s0 *= 0.125f; s1 *= 0.125f;
        float m = fmaxf(s0, s1);
#pragma unroll
        for (int off = 32; off > 0; off >>= 1) m = fmaxf(m, __shfl_xor(m, off));
        float e0 = __expf(s0 - m), e1 = __expf(s1 - m);
        float sum = e0 + e1;
#pragma unroll
        for (int off = 32; off > 0; off >>= 1) sum += __shfl_xor(sum, off);
        float inv = 1.f / sum;
        float p0 = e0 * inv, p1 = e1 * inv;
        float* arow = attnP + ((size_t)(b * H_ + h) * S_ + i) * S_;
        arow[lane] = p0;
        arow[lane + 64] = p1;
        psm[il][lane] = p0;
        psm[il][lane + 64] = p1;   // same-wave readback; no barrier needed
        float acc = 0.f;
        for (int j = 0; j < S_; ++j) acc += psm[il][j] * vb[(size_t)j * D_];
        unsigned short sh, sl;
        split2(acc, sh, sl);
        size_t o = (size_t)(b * S_ + i) * D_ + h * DH_ + lane;
        ch[o] = sh; cl[o] = sl;
    }
}

// ---------------- Fused relation classifier + RGCN aggregate: one block per (b,v) ----------------
__global__ __launch_bounds__(512) void mbuild_edge_kernel(const float* __restrict__ nu,
                                                          const float* __restrict__ a_part,
                                                          const float* __restrict__ b_part,
                                                          const float* __restrict__ rc_b1,
                                                          const float* __restrict__ rc_w2,
                                                          const float* __restrict__ rc_b2,
                                                          const unsigned long long* __restrict__ adjm,
                                                          unsigned short* __restrict__ Mh,
                                                          unsigned short* __restrict__ Ml) {
    __shared__ float acc[R_ * D_];   // 16 KB
    __shared__ float w2t[R_][D_];    // 16 KB, [r][d]
    __shared__ float bsm[D_];        // 2 KB: b_part row for this v
    __shared__ int rl[S_];
    int blk = blockIdx.x;            // b*S + v
    int vv = blk & (S_ - 1);
    int b = blk >> 7;
    int t = threadIdx.x;             // 512
    int w = t >> 6, lane = t & 63;
    for (int i = t; i < R_ * D_; i += 512) {
        w2t[i & 7][i >> 3] = rc_w2[i];
        acc[i] = 0.f;
    }
    bsm[t] = b_part[(size_t)blk * D_ + t];
    __syncthreads();
    // phase 1: rel for u = w, w+8, ... (wave-uniform branch on adjacency bit)
    int wsel = vv >> 6, bsh = vv & 63;
    for (int u = w; u < S_; u += 8) {
        unsigned long long word = adjm[((size_t)(b * S_ + u)) * 2 + wsel];
        if ((word >> bsh) & 1ull) {
            const float* ap = a_part + (size_t)(b * S_ + u) * D_;
            float lp[R_];
#pragma unroll
            for (int r = 0; r < R_; ++r) lp[r] = 0.f;
#pragma unroll
            for (int jj = 0; jj < D_ / 64; ++jj) {
                int d = lane + jj * 64;
                float hv = fmaxf(ap[d] + bsm[d] + rc_b1[d], 0.f);
#pragma unroll
                for (int r = 0; r < R_; ++r) lp[r] += hv * w2t[r][d];
            }
#pragma unroll
            for (int r = 0; r < R_; ++r) {
#pragma unroll
                for (int off = 32; off > 0; off >>= 1) lp[r] += __shfl_down(lp[r], off);
            }
            if (lane == 0) {
                float best = lp[0] + rc_b2[0];
                int bi = 0;
#pragma unroll
                for (int r = 1; r < R_; ++r) {
                    float L = lp[r] + rc_b2[r];
                    if (L > best) { best = L; bi = r; }
                }
                rl[u] = bi;
            }
        } else if (lane == 0) {
            rl[u] = 0;
        }
    }
    __syncthreads();
    // phase 2: u-ascending accumulate; thread t owns element d = t (D_ == 512)
    for (int u = 0; u < S_; ++u) {
        int r = rl[u];
        if (r > 0) acc[r * D_ + t] += nu[(size_t)(b * S_ + u) * D_ + t];
    }
    __syncthreads();
    unsigned short* Hrow = Mh + (size_t)blk * (R_ * D_);
    unsigned short* Lrow = Ml + (size_t)blk * (R_ * D_);
    for (int i = t; i < R_ * D_; i += 512) {
        unsigned short sh, sl;
        split2(acc[i], sh, sl);
        Hrow[i] = sh; Lrow[i] = sl;
    }
}

// ---------------- s2n reduce (4 partials + bias) fused with LayerNorm 2 -> fp32 out ----------------
__global__ void reduceln_kernel(const float* __restrict__ part, const float* __restrict__ x,
                                const float* __restrict__ sb, const float* __restrict__ g,
                                const float* __restrict__ be, float* __restrict__ out) {
    int row = blockIdx.x;
    int t = threadIdx.x;
    __shared__ float red[256];
    float y0 = sb[t], y1 = sb[t + 256];
#pragma unroll
    for (int z = 0; z < 4; ++z) {
        y0 += part[(size_t)z * BSD_ + (size_t)row * D_ + t];
        y1 += part[(size_t)z * BSD_ + (size_t)row * D_ + t + 256];
    }
    float v0 = x[(size_t)row * D_ + t]       + y0;
    float v1 = x[(size_t)row * D_ + t + 256] + y1;
    red[t] = v0 + v1;
    __syncthreads();
    for (int off = 128; off > 0; off >>= 1) {
        if (t < off) red[t] += red[t + off];
        __syncthreads();
    }
    float mean = red[0] * (1.0f / D_);
    __syncthreads();
    float d0 = v0 - mean, d1 = v1 - mean;
    red[t] = d0 * d0 + d1 * d1;
    __syncthreads();
    for (int off = 128; off > 0; off >>= 1) {
        if (t < off) red[t] += red[t + off];
        __syncthreads();
    }
    float rs = rsqrtf(red[0] * (1.0f / D_) + 1e-5f);
    out[(size_t)row * D_ + t]       = d0 * rs * g[t]       + be[t];
    out[(size_t)row * D_ + t + 256] = d1 * rs * g[t + 256] + be[t + 256];
}

extern "C" void kernel_launch(void* const* d_in, const int* in_sizes, int n_in,
                              void* d_out, int out_size, void* d_ws, size_t ws_size,
                              hipStream_t stream) {
    const float* x     = (const float*)d_in[0];
    const float* ln1_g = (const float*)d_in[1];
    const float* ln1_b = (const float*)d_in[2];
    const float* wq    = (const float*)d_in[3];
    const float* bq    = (const float*)d_in[4];
    const float* wk    = (const float*)d_in[5];
    const float* bk    = (const float*)d_in[6];
    const float* wv    = (const float*)d_in[7];
    const float* bv    = (const float*)d_in[8];
    const float* wo    = (const float*)d_in[9];
    const float* bo    = (const float*)d_in[10];
    const float* w1    = (const float*)d_in[11];
    const float* b1    = (const float*)d_in[12];
    const float* w2    = (const float*)d_in[13];
    const float* b2    = (const float*)d_in[14];
    const float* rc_w1 = (const float*)d_in[15];
    const float* rc_b1 = (const float*)d_in[16];
    const float* rc_w2 = (const float*)d_in[17];
    const float* rc_b2 = (const float*)d_in[18];
    const float* kg_w  = (const float*)d_in[19];
    const float* s2n_w = (const float*)d_in[20];
    const float* s2n_b = (const float*)d_in[21];
    const float* ln2_g = (const float*)d_in[22];
    const float* ln2_b = (const float*)d_in[23];
    float* out = (float*)d_out;

    const int BS  = BS_;              // 512
    const int BSD = BSD_;             // 262144

    // ---- Workspace layout ----
    unsigned short* wt = (unsigned short*)d_ws;
    unsigned short* qkv_h = wt;
    unsigned short* qkv_l = wt + 3 * E_;
    unsigned short* wo_h  = wt + 6 * E_;
    unsigned short* wo_l  = wt + 7 * E_;
    unsigned short* w1_h  = wt + 8 * E_;
    unsigned short* w1_l  = wt + 12 * E_;
    unsigned short* w2_h  = wt + 16 * E_;
    unsigned short* w2_l  = wt + 20 * E_;
    unsigned short* rc_h  = wt + 24 * E_;
    unsigned short* rc_l  = wt + 26 * E_;
    unsigned short* kg_h  = wt + 28 * E_;
    unsigned short* kg_l  = wt + 36 * E_;
    unsigned short* s2_h  = wt + 44 * E_;
    unsigned short* s2_l  = wt + 45 * E_;

    // activation bf16 h/l buffers
    unsigned short* xn_h  = wt + 46 * E_;
    unsigned short* xn_l  = xn_h + BSD;
    unsigned short* ctx_h = xn_l + BSD;
    unsigned short* ctx_l = ctx_h + BSD;
    unsigned short* ao_h  = ctx_l + BSD;
    unsigned short* ao_l  = ao_h + BSD;
    unsigned short* hid_h = ao_l + BSD;              // BS*F
    unsigned short* hid_l = hid_h + (size_t)BS * F_;
    unsigned short* nu_h  = hid_l + (size_t)BS * F_;
    unsigned short* nu_l  = nu_h + BSD;
    unsigned short* mb_h  = nu_l + BSD;              // BS*R*D
    unsigned short* mb_l  = mb_h + (size_t)BS * R_ * D_;
    unsigned short* rs_h  = mb_l + (size_t)BS * R_ * D_;
    unsigned short* rs_l  = rs_h + BSD;

    float* fbase  = (float*)(rs_l + BSD);
    float* q      = fbase;                           // q,k,v slabs (3*BSD)
    float* v_     = q + 2 * BSD;
    float* apart  = q + 3 * BSD;                     // a_part,b_part
    float* nu     = apart + 2 * BSD;
    float* y      = nu + BSD;                        // (unused; layout stability)
    float* part4  = y + BSD;                         // 4*BSD (FFN2 partials, then s2n partials)
    float* part8  = part4 + 4 * BSD;                 // 8*BSD
    float* attnP  = part8 + 8 * BSD;                 // B*H*S*S = 2097152

    unsigned long long* adjm = (unsigned long long*)(attnP + 2097152);   // BS*2 ulls

    // 0. transpose+split all weights + LN1 (fused)
    TPack tp;
    int off = 0;
    auto setd = [&](int i, const float* s, unsigned short* h, unsigned short* l, int K, int N) {
        tp.d[i] = TDesc{s, h, l, K, N, off};
        off += (K / 32) * (N / 32);
    };
    setd(0, wq, qkv_h,          qkv_l,          D_, D_);
    setd(1, wk, qkv_h + E_,     qkv_l + E_,     D_, D_);
    setd(2, wv, qkv_h + 2 * E_, qkv_l + 2 * E_, D_, D_);
    setd(3, wo, wo_h, wo_l, D_, D_);
    setd(4, w1, w1_h, w1_l, D_, F_);
    setd(5, w2, w2_h, w2_l, F_, D_);
    setd(6, rc_w1,            rc_h,      rc_l,      D_, D_);
    setd(7, rc_w1 + D_ * D_,  rc_h + E_, rc_l + E_, D_, D_);
    setd(8, kg_w, kg_h, kg_l, R_ * D_, D_);
    setd(9, s2n_w, s2_h, s2_l, D_, D_);
    hipLaunchKernelGGL(prep_kernel, dim3(off + BS), dim3(256), 0, stream, tp, off,
                       x, ln1_g, ln1_b, xn_h, xn_l);

    // 1. QKV (z-batched) -> q,k,v fp32
    hipLaunchKernelGGL(mgemm_zw_kernel, dim3(D_ / 64, BS / 64, 3), dim3(256), 0, stream,
                       xn_h, xn_l, qkv_h, qkv_l, bq, bk, bv, q, BS, D_, D_);
    // 2. attention v2 -> attnP, ctx h/l
    hipLaunchKernelGGL(attn_kernel2, dim3(B_ * H_ * 8), dim3(512), 0, stream,
                       q, q + BSD, v_, attnP, ctx_h, ctx_l);
    // 3. wo GEMM + adjacency bitmask (fused) -> ao h/l, adjm
    hipLaunchKernelGGL(wo_adj_kernel, dim3(64 + 256), dim3(256), 0, stream,
                       ctx_h, ctx_l, wo_h, wo_l, bo, ao_h, ao_l, attnP, adjm);
    // 4. FFN1 (relu): attn_out -> hidden h/l
    hipLaunchKernelGGL(mgemm_kernel, dim3(F_ / 64, BS / 64), dim3(256), 0, stream,
                       ao_h, ao_l, w1_h, w1_l, b1, (float*)nullptr, hid_h, hid_l, F_, D_, 1);
    // 5. FFN2 split-K=4 partials
    hipLaunchKernelGGL(mgemm_part_kernel, dim3(D_ / 64, BS / 64, 4), dim3(256), 0, stream,
                       hid_h, hid_l, w2_h, w2_l, part4, BS, D_, F_);
    // 5b. reduce + bias -> nu fp32 + h/l
    hipLaunchKernelGGL(reduce4_kernel, dim3(BSD / 1024), dim3(256), 0, stream,
                       part4, b2, nu, nu_h, nu_l);
    // 6. rc halves (z-batched) -> a_part,b_part fp32
    hipLaunchKernelGGL(mgemm_zw_kernel, dim3(D_ / 64, BS / 64, 2), dim3(256), 0, stream,
                       nu_h, nu_l, rc_h, rc_l, (const float*)nullptr, (const float*)nullptr,
                       (const float*)nullptr, apart, BS, D_, D_);
    // 7. fused relation classifier + RGCN aggregate -> Mbuf h/l
    hipLaunchKernelGGL(mbuild_edge_kernel, dim3(BS), dim3(512), 0, stream,
                       nu, apart, apart + BSD, rc_b1, rc_w2, rc_b2, adjm, mb_h, mb_l);
    // 8. Mbuf @ kg_w split-K=8 partials
    hipLaunchKernelGGL(mgemm_part_kernel, dim3(D_ / 64, BS / 64, 8), dim3(256), 0, stream,
                       mb_h, mb_l, kg_h, kg_l, part8, BS, D_, R_ * D_);
    // 8b. reduce + residual (nu) -> reasoned h/l
    hipLaunchKernelGGL(reduce8_kernel, dim3(BSD / 1024), dim3(256), 0, stream,
                       part8, nu, rs_h, rs_l);
    // 9. s2n split-K=4 partials (256 blocks)
    hipLaunchKernelGGL(mgemm_part_kernel, dim3(D_ / 64, BS / 64, 4), dim3(256), 0, stream,
                       rs_h, rs_l, s2_h, s2_l, part4, BS, D_, D_);
    // 10. s2n-reduce + LN2 (fused) -> out
    hipLaunchKernelGGL(reduceln_kernel, dim3(BS), dim3(256), 0, stream,
                       part4, x, s2n_b, ln2_g, ln2_b, out);
}

// Round 17
// 215.593 us; speedup vs baseline: 1.0118x; 1.0118x over previous
//
#include <hip/hip_runtime.h>
#include <hip/hip_bf16.h>

#define B_ 4
#define S_ 128
#define D_ 512
#define H_ 8
#define DH_ 64
#define F_ 2048
#define R_ 8
#define BS_ (B_ * S_)
#define BSD_ (BS_ * D_)
#define E_ 262144          // 512*512

typedef __attribute__((ext_vector_type(8))) short short8;
typedef __attribute__((ext_vector_type(4))) float f32x4;
typedef __attribute__((ext_vector_type(4))) unsigned short ushort4v;

// fp32 -> bf16 hi (RNE) + bf16 lo (RNE of exact residual)
__device__ __forceinline__ void split2(float a, unsigned short& h, unsigned short& l) {
    unsigned u = __float_as_uint(a);
    unsigned hr = (u + 0x7FFFu + ((u >> 16) & 1u)) >> 16;
    h = (unsigned short)hr;
    float lo = a - __uint_as_float(hr << 16);
    unsigned u2 = __float_as_uint(lo);
    l = (unsigned short)((u2 + 0x7FFFu + ((u2 >> 16) & 1u)) >> 16);
}

// ---------------- prep: weight transpose+split (blocks < nt) + LN1 (rest) ----------------
struct TDesc { const float* s; unsigned short* h; unsigned short* l; int K; int N; int off; };
struct TPack { TDesc d[10]; };

__global__ void prep_kernel(TPack p, int nt, const float* __restrict__ x,
                            const float* __restrict__ g, const float* __restrict__ be,
                            unsigned short* __restrict__ xh, unsigned short* __restrict__ xl) {
    __shared__ float tr[32][33];
    __shared__ float red[256];
    int bid = blockIdx.x;
    if (bid < nt) {
        int wi = 0;
#pragma unroll
        for (int i = 1; i < 10; ++i) if (bid >= p.d[i].off) wi = i;
        const TDesc dd = p.d[wi];
        int t = bid - dd.off;
        int ntk = dd.K / 32;
        int tk = t % ntk, tn = t / ntk;
        int k0 = tk * 32, n0 = tn * 32;
        int col = threadIdx.x & 31, rg = threadIdx.x >> 5;   // rg 0..7
#pragma unroll
        for (int i = 0; i < 4; ++i) {
            int row = rg * 4 + i;
            tr[row][col] = dd.s[(size_t)(k0 + row) * dd.N + n0 + col];
        }
        __syncthreads();
#pragma unroll
        for (int i = 0; i < 4; ++i) {
            int n = n0 + rg * 4 + i;
            int k = k0 + col;
            unsigned short h, l;
            split2(tr[col][rg * 4 + i], h, l);
            dd.h[(size_t)n * dd.K + k] = h;
            dd.l[(size_t)n * dd.K + k] = l;
        }
    } else {
        int row = bid - nt;
        int t = threadIdx.x;
        const float* xr = x + (size_t)row * D_;
        float v0 = xr[t], v1 = xr[t + 256];
        red[t] = v0 + v1;
        __syncthreads();
        for (int off = 128; off > 0; off >>= 1) { if (t < off) red[t] += red[t + off]; __syncthreads(); }
        float mean = red[0] * (1.0f / D_);
        __syncthreads();
        float d0 = v0 - mean, d1 = v1 - mean;
        red[t] = d0 * d0 + d1 * d1;
        __syncthreads();
        for (int off = 128; off > 0; off >>= 1) { if (t < off) red[t] += red[t + off]; __syncthreads(); }
        float rs = rsqrtf(red[0] * (1.0f / D_) + 1e-5f);
        float o0 = d0 * rs * g[t] + be[t];
        float o1 = d1 * rs * g[t + 256] + be[t + 256];
        unsigned short h, l;
        split2(o0, h, l); xh[(size_t)row * D_ + t] = h;       xl[(size_t)row * D_ + t] = l;
        split2(o1, h, l); xh[(size_t)row * D_ + t + 256] = h; xl[(size_t)row * D_ + t + 256] = l;
    }
}

// ---------------- MFMA bf16x3 GEMM core: BK=64, 3-buf DMA pipeline, ONE barrier/step ----------------
// XOR swizzle (both-sides, rule21): linear DMA dest; SOURCE chunk ^= (row&7); READ chunk ^= (row&7).
// Invariant: a wave reaches step-s's barrier only after finishing step-(s-1)'s LDS reads, so
// restaging buf (s-1)%3 == (s+2)%3 AFTER the barrier cannot race any reader. One s_barrier/step.
// vmcnt: outstanding entering step s = {batch s, batch s+1} -> vmcnt(8) retires batch s exactly.
struct GemmLds {
    unsigned short A[3][2][64][64];    // [buf][hi/lo][row][k]  (8192 ushorts per buf)
    unsigned short B[3][2][64][64];
};                                     // 98304 bytes (1 block/CU; all grids <= 320 blocks)

__device__ __forceinline__ void gload16(const unsigned short* g, unsigned short* l) {
    __builtin_amdgcn_global_load_lds(
        (const __attribute__((address_space(1))) void*)g,
        (__attribute__((address_space(3))) void*)l, 16, 0, 0);
}

__device__ __forceinline__ void mgemm_core(const unsigned short* __restrict__ Ath,
                                           const unsigned short* __restrict__ Atl,
                                           const unsigned short* __restrict__ Bth,
                                           const unsigned short* __restrict__ Btl,
                                           int K, int rowBase, int colBase,
                                           int kStart, int nsteps,   // nsteps = kLen/64
                                           f32x4 acc[2][2], GemmLds* L) {
    int tid = threadIdx.x;
    int w = tid >> 6, lane = tid & 63;
    int lm = lane & 15, quad = lane >> 4;
    int wm = (w & 1) * 32, wn = (w >> 1) * 32;
    int r0 = w * 8 + (lane >> 3);                 // staged row (half 0); half 1 = +32
    int lc = ((lane & 7) ^ (lane >> 3)) * 8;      // swizzled source col (involution)
    int wb = w * 512;                             // wave's ushort offset within 4096B half
    size_t a0 = (size_t)(rowBase + r0) * K + kStart + lc;
    size_t a1 = (size_t)(rowBase + r0 + 32) * K + kStart + lc;
    size_t b0 = (size_t)(colBase + r0) * K + kStart + lc;
    size_t b1 = (size_t)(colBase + r0 + 32) * K + kStart + lc;
    unsigned short* AB = &L->A[0][0][0][0];
    unsigned short* BB = &L->B[0][0][0][0];
    auto stage = [&](int buf, size_t koff) {      // 8 vmem ops per call
        gload16(&Ath[a0 + koff], AB + buf * 8192 + wb);
        gload16(&Ath[a1 + koff], AB + buf * 8192 + 2048 + wb);
        gload16(&Atl[a0 + koff], AB + buf * 8192 + 4096 + wb);
        gload16(&Atl[a1 + koff], AB + buf * 8192 + 6144 + wb);
        gload16(&Bth[b0 + koff], BB + buf * 8192 + wb);
        gload16(&Bth[b1 + koff], BB + buf * 8192 + 2048 + wb);
        gload16(&Btl[b0 + koff], BB + buf * 8192 + 4096 + wb);
        gload16(&Btl[b1 + koff], BB + buf * 8192 + 6144 + wb);
    };
    // prologue: 2 batches in flight
    stage(0, 0);
    if (nsteps > 1) stage(1, 64);
    for (int s = 0; s < nsteps; ++s) {
        int b = s % 3;
        if (s + 2 <= nsteps) asm volatile("s_waitcnt vmcnt(8)" ::: "memory");  // retire batch s
        else                 asm volatile("s_waitcnt vmcnt(0)" ::: "memory");  // last step
        __builtin_amdgcn_s_barrier();             // all waves' buf-b DMA landed
        __builtin_amdgcn_sched_barrier(0);
        if (s + 2 < nsteps) stage((s + 2) % 3, (size_t)(s + 2) * 64);  // overlaps reads+MFMA
#pragma unroll
        for (int sub = 0; sub < 2; ++sub) {
            short8 ah[2], al[2], bh[2], bl[2];
            int pc = ((sub * 4 + quad) ^ (lm & 7)) * 8;          // swizzled read chunk
#pragma unroll
            for (int t = 0; t < 2; ++t) {
                int ra = (wm + t * 16 + lm) * 64 + pc;
                int rb = (wn + t * 16 + lm) * 64 + pc;
                ah[t] = *(const short8*)(AB + b * 8192 + ra);
                al[t] = *(const short8*)(AB + b * 8192 + 4096 + ra);
                bh[t] = *(const short8*)(BB + b * 8192 + rb);
                bl[t] = *(const short8*)(BB + b * 8192 + 4096 + rb);
            }
#pragma unroll
            for (int tm = 0; tm < 2; ++tm)
#pragma unroll
                for (int tn = 0; tn < 2; ++tn) {
                    acc[tm][tn] = __builtin_amdgcn_mfma_f32_16x16x32_bf16(ah[tm], bh[tn], acc[tm][tn], 0, 0, 0);
                    acc[tm][tn] = __builtin_amdgcn_mfma_f32_16x16x32_bf16(ah[tm], bl[tn], acc[tm][tn], 0, 0, 0);
                    acc[tm][tn] = __builtin_amdgcn_mfma_f32_16x16x32_bf16(al[tm], bh[tn], acc[tm][tn], 0, 0, 0);
                }
        }
        __builtin_amdgcn_sched_barrier(0);
    }
}

__device__ __forceinline__ void gemm_epilogue(f32x4 acc[2][2], const float* bias,
                                              float* Cf, unsigned short* Ch, unsigned short* Cl,
                                              int N, int relu, int rowBase, int colBase) {
    int tid = threadIdx.x;
    int w = tid >> 6, lane = tid & 63;
    int lm = lane & 15, quad = lane >> 4;
    int wm = (w & 1) * 32, wn = (w >> 1) * 32;
#pragma unroll
    for (int tm = 0; tm < 2; ++tm)
#pragma unroll
        for (int tn = 0; tn < 2; ++tn) {
            int col = colBase + wn + tn * 16 + lm;
            float bi = bias ? bias[col] : 0.f;
#pragma unroll
            for (int r = 0; r < 4; ++r) {
                int row = rowBase + wm + tm * 16 + quad * 4 + r;
                float v = acc[tm][tn][r] + bi;
                if (relu) v = fmaxf(v, 0.f);
                size_t o = (size_t)row * N + col;
                if (Cf) Cf[o] = v;
                if (Ch) {
                    unsigned short sh, sl;
                    split2(v, sh, sl);
                    Ch[o] = sh; Cl[o] = sl;
                }
            }
        }
}

// Generic GEMM: optional fp32 out, optional pre-split bf16 h/l out.
__global__ __launch_bounds__(256) void mgemm_kernel(const unsigned short* __restrict__ Ath,
                                                    const unsigned short* __restrict__ Atl,
                                                    const unsigned short* __restrict__ Bth,
                                                    const unsigned short* __restrict__ Btl,
                                                    const float* __restrict__ bias,
                                                    float* __restrict__ Cf,
                                                    unsigned short* __restrict__ Ch,
                                                    unsigned short* __restrict__ Cl,
                                                    int N, int K, int relu) {
    __shared__ GemmLds L;
    int rowBase = blockIdx.y * 64, colBase = blockIdx.x * 64;
    f32x4 acc[2][2] = {};
    mgemm_core(Ath, Atl, Bth, Btl, K, rowBase, colBase, 0, K / 64, acc, &L);
    gemm_epilogue(acc, bias, Cf, Ch, Cl, N, relu, rowBase, colBase);
}

// z-batched GEMM over weight slabs (QKV: 3, rc halves: 2); fp32 out only.
__global__ __launch_bounds__(256) void mgemm_zw_kernel(const unsigned short* __restrict__ Ath,
                                                       const unsigned short* __restrict__ Atl,
                                                       const unsigned short* __restrict__ Bth,
                                                       const unsigned short* __restrict__ Btl,
                                                       const float* __restrict__ b0,
                                                       const float* __restrict__ b1,
                                                       const float* __restrict__ b2,
                                                       float* __restrict__ Cbase,
                                                       int M, int N, int K) {
    __shared__ GemmLds L;
    int z = blockIdx.z;
    const unsigned short* bth = Bth + (size_t)z * K * N;
    const unsigned short* btl = Btl + (size_t)z * K * N;
    const float* bias = (z == 0) ? b0 : (z == 1) ? b1 : b2;
    float* C = Cbase + (size_t)z * M * N;
    int rowBase = blockIdx.y * 64, colBase = blockIdx.x * 64;
    f32x4 acc[2][2] = {};
    mgemm_core(Ath, Atl, bth, btl, K, rowBase, colBase, 0, K / 64, acc, &L);
    gemm_epilogue(acc, bias, C, nullptr, nullptr, N, 0, rowBase, colBase);
}

// split-K partial GEMM: each z-slice writes its own fp32 slab (no atomics).
__global__ __launch_bounds__(256) void mgemm_part_kernel(const unsigned short* __restrict__ Ath,
                                                         const unsigned short* __restrict__ Atl,
                                                         const unsigned short* __restrict__ Bth,
                                                         const unsigned short* __restrict__ Btl,
                                                         float* __restrict__ Cbase,
                                                         int M, int N, int K) {
    __shared__ GemmLds L;
    int ks = gridDim.z, z = blockIdx.z;
    int kLen = K / ks, kStart = z * kLen;
    float* C = Cbase + (size_t)z * M * N;
    int rowBase = blockIdx.y * 64, colBase = blockIdx.x * 64;
    f32x4 acc[2][2] = {};
    mgemm_core(Ath, Atl, Bth, Btl, K, rowBase, colBase, kStart, kLen / 64, acc, &L);
    gemm_epilogue(acc, nullptr, C, nullptr, nullptr, N, 0, rowBase, colBase);
}

// wo GEMM (blocks 0..63) + adjacency bitmask via ballot (blocks 64..319)
__global__ __launch_bounds__(256) void wo_adj_kernel(const unsigned short* __restrict__ Ath,
                                                     const unsigned short* __restrict__ Atl,
                                                     const unsigned short* __restrict__ Bth,
                                                     const unsigned short* __restrict__ Btl,
                                                     const float* __restrict__ bias,
                                                     unsigned short* __restrict__ Ch,
                                                     unsigned short* __restrict__ Cl,
                                                     const float* __restrict__ attnP,
                                                     unsigned long long* __restrict__ adjm) {
    __shared__ GemmLds L;
    int bid = blockIdx.x;
    if (bid < 64) {
        int rowBase = (bid >> 3) * 64, colBase = (bid & 7) * 64;
        f32x4 acc[2][2] = {};
        mgemm_core(Ath, Atl, Bth, Btl, D_, rowBase, colBase, 0, D_ / 64, acc, &L);
        gemm_epilogue(acc, bias, nullptr, Ch, Cl, D_, 0, rowBase, colBase);
    } else {
        int idx = (bid - 64) * 256 + threadIdx.x;   // (b*S + i)*S + j
        int j = idx & (S_ - 1);
        int bi = idx >> 7;                           // row = b*S + i
        int i = bi & (S_ - 1);
        int b = bi >> 7;
        float s = 0.f;
#pragma unroll
        for (int h = 0; h < H_; ++h) s += attnP[(((size_t)(b * H_ + h)) * S_ + i) * S_ + j];
        s *= (1.0f / H_);
        int pred = (s > 0.1f && i != j) ? 1 : 0;
        unsigned long long m = __ballot(pred);
        if ((threadIdx.x & 63) == 0)
            adjm[(size_t)bi * 2 + ((threadIdx.x >> 6) & 1)] = m;
    }
}

// sum 4 partials + bias -> nu fp32 + bf16 h/l
__global__ void reduce4_kernel(const float* __restrict__ part, const float* __restrict__ b2,
                               float* __restrict__ nu,
                               unsigned short* __restrict__ nh, unsigned short* __restrict__ nl) {
    int base = blockIdx.x * 1024 + threadIdx.x * 4;
    f32x4 s = *(const f32x4*)&b2[base & (D_ - 1)];
#pragma unroll
    for (int z = 0; z < 4; ++z) s += *(const f32x4*)&part[(size_t)z * BSD_ + base];
    *(f32x4*)&nu[base] = s;
    ushort4v hv, lv;
#pragma unroll
    for (int i = 0; i < 4; ++i) { unsigned short h, l; split2(s[i], h, l); hv[i] = h; lv[i] = l; }
    *(ushort4v*)&nh[base] = hv;
    *(ushort4v*)&nl[base] = lv;
}

// reasoned = nu + sum 8 partials -> bf16 h/l only
__global__ void reduce8_kernel(const float* __restrict__ part, const float* __restrict__ nu,
                               unsigned short* __restrict__ rh, unsigned short* __restrict__ rl) {
    int base = blockIdx.x * 1024 + threadIdx.x * 4;
    f32x4 s = *(const f32x4*)&nu[base];
#pragma unroll
    for (int z = 0; z < 8; ++z) s += *(const f32x4*)&part[(size_t)z * BSD_ + base];
    ushort4v hv, lv;
#pragma unroll
    for (int i = 0; i < 4; ++i) { unsigned short h, l; split2(s[i], h, l); hv[i] = h; lv[i] = l; }
    *(ushort4v*)&rh[base] = hv;
    *(ushort4v*)&rl[base] = lv;
}

// ---------------- Attention v2: block = (b,h,16 i's); K tile LDS-staged, conflict-free dot ----------------
__global__ __launch_bounds__(512) void attn_kernel2(const float* __restrict__ q,
                                                    const float* __restrict__ k,
                                                    const float* __restrict__ v,
                                                    float* __restrict__ attnP,
                                                    unsigned short* __restrict__ ch,
                                                    unsigned short* __restrict__ cl) {
    __shared__ float ksm[S_][DH_ + 3];   // [128][67]
    __shared__ float qsm[16][DH_];
    __shared__ float psm[16][S_];
    int tid = threadIdx.x;
    int w = tid >> 6, lane = tid & 63;
    int blk = blockIdx.x;                // ((b*H + h)*8 + ig)
    int ig = blk & 7;
    int bh = blk >> 3;
    int h = bh & (H_ - 1);
    int b = bh >> 3;
    int i0 = ig * 16;
    const float* kb = k + (size_t)b * S_ * D_ + h * DH_;
    for (int j = w; j < S_; j += 8) ksm[j][lane] = kb[(size_t)j * D_ + lane];
    for (int il = w; il < 16; il += 8)
        qsm[il][lane] = q[(size_t)(b * S_ + i0 + il) * D_ + h * DH_ + lane];
    __syncthreads();
    const float* vb = v + (size_t)b * S_ * D_ + h * DH_ + lane;
#pragma unroll
    for (int c = 0; c < 2; ++c) {
        int il = w + c * 8;
        int i = i0 + il;
        float s0 = 0.f, s1 = 0.f;
#pragma unroll 8
        for (int d = 0; d < DH_; ++d) {
            float qd = qsm[il][d];
            s0 += qd * ksm[lane][d];
            s1 += qd * ksm[lane + 64][d];
        }
        s0 *= 0.125f; s1 *= 0.125f;
        float m = fmaxf(s0, s1);
#pragma unroll
        for (int off = 32; off > 0; off >>= 1) m = fmaxf(m, __shfl_xor(m, off));
        float e0 = __expf(s0 - m), e1 = __expf(s1 - m);
        float sum = e0 + e1;
#pragma unroll
        for (int off = 32; off > 0; off >>= 1) sum += __shfl_xor(sum, off);
        float inv = 1.f / sum;
        float p0 = e0 * inv, p1 = e1 * inv;
        float* arow = attnP + ((size_t)(b * H_ + h) * S_ + i) * S_;
        arow[lane] = p0;
        arow[lane + 64] = p1;
        psm[il][lane] = p0;
        psm[il][lane + 64] = p1;   // same-wave readback; no barrier needed
        float acc = 0.f;
        for (int j = 0; j < S_; ++j) acc += psm[il][j] * vb[(size_t)j * D_];
        unsigned short sh, sl;
        split2(acc, sh, sl);
        size_t o = (size_t)(b * S_ + i) * D_ + h * DH_ + lane;
        ch[o] = sh; cl[o] = sl;
    }
}

// ---------------- Fused relation classifier + RGCN aggregate: one block per (b,v) ----------------
__global__ __launch_bounds__(512) void mbuild_edge_kernel(const float* __restrict__ nu,
                                                          const float* __restrict__ a_part,
                                                          const float* __restrict__ b_part,
                                                          const float* __restrict__ rc_b1,
                                                          const float* __restrict__ rc_w2,
                                                          const float* __restrict__ rc_b2,
                                                          const unsigned long long* __restrict__ adjm,
                                                          unsigned short* __restrict__ Mh,
                                                          unsigned short* __restrict__ Ml) {
    __shared__ float acc[R_ * D_];   // 16 KB
    __shared__ float w2t[R_][D_];    // 16 KB, [r][d]
    __shared__ float bsm[D_];        // 2 KB: b_part row for this v
    __shared__ int rl[S_];
    int blk = blockIdx.x;            // b*S + v
    int vv = blk & (S_ - 1);
    int b = blk >> 7;
    int t = threadIdx.x;             // 512
    int w = t >> 6, lane = t & 63;
    for (int i = t; i < R_ * D_; i += 512) {
        w2t[i & 7][i >> 3] = rc_w2[i];
        acc[i] = 0.f;
    }
    bsm[t] = b_part[(size_t)blk * D_ + t];
    __syncthreads();
    // phase 1: rel for u = w, w+8, ... (wave-uniform branch on adjacency bit)
    int wsel = vv >> 6, bsh = vv & 63;
    for (int u = w; u < S_; u += 8) {
        unsigned long long word = adjm[((size_t)(b * S_ + u)) * 2 + wsel];
        if ((word >> bsh) & 1ull) {
            const float* ap = a_part + (size_t)(b * S_ + u) * D_;
            float lp[R_];
#pragma unroll
            for (int r = 0; r < R_; ++r) lp[r] = 0.f;
#pragma unroll
            for (int jj = 0; jj < D_ / 64; ++jj) {
                int d = lane + jj * 64;
                float hv = fmaxf(ap[d] + bsm[d] + rc_b1[d], 0.f);
#pragma unroll
                for (int r = 0; r < R_; ++r) lp[r] += hv * w2t[r][d];
            }
#pragma unroll
            for (int r = 0; r < R_; ++r) {
#pragma unroll
                for (int off = 32; off > 0; off >>= 1) lp[r] += __shfl_down(lp[r], off);
            }
            if (lane == 0) {
                float best = lp[0] + rc_b2[0];
                int bi = 0;
#pragma unroll
                for (int r = 1; r < R_; ++r) {
                    float L = lp[r] + rc_b2[r];
                    if (L > best) { best = L; bi = r; }
                }
                rl[u] = bi;
            }
        } else if (lane == 0) {
            rl[u] = 0;
        }
    }
    __syncthreads();
    // phase 2: u-ascending accumulate; thread t owns element d = t (D_ == 512)
    for (int u = 0; u < S_; ++u) {
        int r = rl[u];
        if (r > 0) acc[r * D_ + t] += nu[(size_t)(b * S_ + u) * D_ + t];
    }
    __syncthreads();
    unsigned short* Hrow = Mh + (size_t)blk * (R_ * D_);
    unsigned short* Lrow = Ml + (size_t)blk * (R_ * D_);
    for (int i = t; i < R_ * D_; i += 512) {
        unsigned short sh, sl;
        split2(acc[i], sh, sl);
        Hrow[i] = sh; Lrow[i] = sl;
    }
}

// ---------------- s2n reduce (4 partials + bias) fused with LayerNorm 2 -> fp32 out ----------------
__global__ void reduceln_kernel(const float* __restrict__ part, const float* __restrict__ x,
                                const float* __restrict__ sb, const float* __restrict__ g,
                                const float* __restrict__ be, float* __restrict__ out) {
    int row = blockIdx.x;
    int t = threadIdx.x;
    __shared__ float red[256];
    float y0 = sb[t], y1 = sb[t + 256];
#pragma unroll
    for (int z = 0; z < 4; ++z) {
        y0 += part[(size_t)z * BSD_ + (size_t)row * D_ + t];
        y1 += part[(size_t)z * BSD_ + (size_t)row * D_ + t + 256];
    }
    float v0 = x[(size_t)row * D_ + t]       + y0;
    float v1 = x[(size_t)row * D_ + t + 256] + y1;
    red[t] = v0 + v1;
    __syncthreads();
    for (int off = 128; off > 0; off >>= 1) {
        if (t < off) red[t] += red[t + off];
        __syncthreads();
    }
    float mean = red[0] * (1.0f / D_);
    __syncthreads();
    float d0 = v0 - mean, d1 = v1 - mean;
    red[t] = d0 * d0 + d1 * d1;
    __syncthreads();
    for (int off = 128; off > 0; off >>= 1) {
        if (t < off) red[t] += red[t + off];
        __syncthreads();
    }
    float rs = rsqrtf(red[0] * (1.0f / D_) + 1e-5f);
    out[(size_t)row * D_ + t]       = d0 * rs * g[t]       + be[t];
    out[(size_t)row * D_ + t + 256] = d1 * rs * g[t + 256] + be[t + 256];
}

extern "C" void kernel_launch(void* const* d_in, const int* in_sizes, int n_in,
                              void* d_out, int out_size, void* d_ws, size_t ws_size,
                              hipStream_t stream) {
    const float* x     = (const float*)d_in[0];
    const float* ln1_g = (const float*)d_in[1];
    const float* ln1_b = (const float*)d_in[2];
    const float* wq    = (const float*)d_in[3];
    const float* bq    = (const float*)d_in[4];
    const float* wk    = (const float*)d_in[5];
    const float* bk    = (const float*)d_in[6];
    const float* wv    = (const float*)d_in[7];
    const float* bv    = (const float*)d_in[8];
    const float* wo    = (const float*)d_in[9];
    const float* bo    = (const float*)d_in[10];
    const float* w1    = (const float*)d_in[11];
    const float* b1    = (const float*)d_in[12];
    const float* w2    = (const float*)d_in[13];
    const float* b2    = (const float*)d_in[14];
    const float* rc_w1 = (const float*)d_in[15];
    const float* rc_b1 = (const float*)d_in[16];
    const float* rc_w2 = (const float*)d_in[17];
    const float* rc_b2 = (const float*)d_in[18];
    const float* kg_w  = (const float*)d_in[19];
    const float* s2n_w = (const float*)d_in[20];
    const float* s2n_b = (const float*)d_in[21];
    const float* ln2_g = (const float*)d_in[22];
    const float* ln2_b = (const float*)d_in[23];
    float* out = (float*)d_out;

    const int BS  = BS_;              // 512
    const int BSD = BSD_;             // 262144

    // ---- Workspace layout ----
    unsigned short* wt = (unsigned short*)d_ws;
    unsigned short* qkv_h = wt;
    unsigned short* qkv_l = wt + 3 * E_;
    unsigned short* wo_h  = wt + 6 * E_;
    unsigned short* wo_l  = wt + 7 * E_;
    unsigned short* w1_h  = wt + 8 * E_;
    unsigned short* w1_l  = wt + 12 * E_;
    unsigned short* w2_h  = wt + 16 * E_;
    unsigned short* w2_l  = wt + 20 * E_;
    unsigned short* rc_h  = wt + 24 * E_;
    unsigned short* rc_l  = wt + 26 * E_;
    unsigned short* kg_h  = wt + 28 * E_;
    unsigned short* kg_l  = wt + 36 * E_;
    unsigned short* s2_h  = wt + 44 * E_;
    unsigned short* s2_l  = wt + 45 * E_;

    // activation bf16 h/l buffers
    unsigned short* xn_h  = wt + 46 * E_;
    unsigned short* xn_l  = xn_h + BSD;
    unsigned short* ctx_h = xn_l + BSD;
    unsigned short* ctx_l = ctx_h + BSD;
    unsigned short* ao_h  = ctx_l + BSD;
    unsigned short* ao_l  = ao_h + BSD;
    unsigned short* hid_h = ao_l + BSD;              // BS*F
    unsigned short* hid_l = hid_h + (size_t)BS * F_;
    unsigned short* nu_h  = hid_l + (size_t)BS * F_;
    unsigned short* nu_l  = nu_h + BSD;
    unsigned short* mb_h  = nu_l + BSD;              // BS*R*D
    unsigned short* mb_l  = mb_h + (size_t)BS * R_ * D_;
    unsigned short* rs_h  = mb_l + (size_t)BS * R_ * D_;
    unsigned short* rs_l  = rs_h + BSD;

    float* fbase  = (float*)(rs_l + BSD);
    float* q      = fbase;                           // q,k,v slabs (3*BSD)
    float* v_     = q + 2 * BSD;
    float* apart  = q + 3 * BSD;                     // a_part,b_part
    float* nu     = apart + 2 * BSD;
    float* y      = nu + BSD;                        // (unused; layout stability)
    float* part4  = y + BSD;                         // 4*BSD (FFN2 partials, then s2n partials)
    float* part8  = part4 + 4 * BSD;                 // 8*BSD
    float* attnP  = part8 + 8 * BSD;                 // B*H*S*S = 2097152

    unsigned long long* adjm = (unsigned long long*)(attnP + 2097152);   // BS*2 ulls

    // 0. transpose+split all weights + LN1 (fused)
    TPack tp;
    int off = 0;
    auto setd = [&](int i, const float* s, unsigned short* h, unsigned short* l, int K, int N) {
        tp.d[i] = TDesc{s, h, l, K, N, off};
        off += (K / 32) * (N / 32);
    };
    setd(0, wq, qkv_h,          qkv_l,          D_, D_);
    setd(1, wk, qkv_h + E_,     qkv_l + E_,     D_, D_);
    setd(2, wv, qkv_h + 2 * E_, qkv_l + 2 * E_, D_, D_);
    setd(3, wo, wo_h, wo_l, D_, D_);
    setd(4, w1, w1_h, w1_l, D_, F_);
    setd(5, w2, w2_h, w2_l, F_, D_);
    setd(6, rc_w1,            rc_h,      rc_l,      D_, D_);
    setd(7, rc_w1 + D_ * D_,  rc_h + E_, rc_l + E_, D_, D_);
    setd(8, kg_w, kg_h, kg_l, R_ * D_, D_);
    setd(9, s2n_w, s2_h, s2_l, D_, D_);
    hipLaunchKernelGGL(prep_kernel, dim3(off + BS), dim3(256), 0, stream, tp, off,
                       x, ln1_g, ln1_b, xn_h, xn_l);

    // 1. QKV (z-batched) -> q,k,v fp32
    hipLaunchKernelGGL(mgemm_zw_kernel, dim3(D_ / 64, BS / 64, 3), dim3(256), 0, stream,
                       xn_h, xn_l, qkv_h, qkv_l, bq, bk, bv, q, BS, D_, D_);
    // 2. attention v2 -> attnP, ctx h/l
    hipLaunchKernelGGL(attn_kernel2, dim3(B_ * H_ * 8), dim3(512), 0, stream,
                       q, q + BSD, v_, attnP, ctx_h, ctx_l);
    // 3. wo GEMM + adjacency bitmask (fused) -> ao h/l, adjm
    hipLaunchKernelGGL(wo_adj_kernel, dim3(64 + 256), dim3(256), 0, stream,
                       ctx_h, ctx_l, wo_h, wo_l, bo, ao_h, ao_l, attnP, adjm);
    // 4. FFN1 (relu): attn_out -> hidden h/l
    hipLaunchKernelGGL(mgemm_kernel, dim3(F_ / 64, BS / 64), dim3(256), 0, stream,
                       ao_h, ao_l, w1_h, w1_l, b1, (float*)nullptr, hid_h, hid_l, F_, D_, 1);
    // 5. FFN2 split-K=4 partials
    hipLaunchKernelGGL(mgemm_part_kernel, dim3(D_ / 64, BS / 64, 4), dim3(256), 0, stream,
                       hid_h, hid_l, w2_h, w2_l, part4, BS, D_, F_);
    // 5b. reduce + bias -> nu fp32 + h/l
    hipLaunchKernelGGL(reduce4_kernel, dim3(BSD / 1024), dim3(256), 0, stream,
                       part4, b2, nu, nu_h, nu_l);
    // 6. rc halves (z-batched) -> a_part,b_part fp32
    hipLaunchKernelGGL(mgemm_zw_kernel, dim3(D_ / 64, BS / 64, 2), dim3(256), 0, stream,
                       nu_h, nu_l, rc_h, rc_l, (const float*)nullptr, (const float*)nullptr,
                       (const float*)nullptr, apart, BS, D_, D_);
    // 7. fused relation classifier + RGCN aggregate -> Mbuf h/l
    hipLaunchKernelGGL(mbuild_edge_kernel, dim3(BS), dim3(512), 0, stream,
                       nu, apart, apart + BSD, rc_b1, rc_w2, rc_b2, adjm, mb_h, mb_l);
    // 8. Mbuf @ kg_w split-K=8 partials
    hipLaunchKernelGGL(mgemm_part_kernel, dim3(D_ / 64, BS / 64, 8), dim3(256), 0, stream,
                       mb_h, mb_l, kg_h, kg_l, part8, BS, D_, R_ * D_);
    // 8b. reduce + residual (nu) -> reasoned h/l
    hipLaunchKernelGGL(reduce8_kernel, dim3(BSD / 1024), dim3(256), 0, stream,
                       part8, nu, rs_h, rs_l);
    // 9. s2n split-K=4 partials (256 blocks)
    hipLaunchKernelGGL(mgemm_part_kernel, dim3(D_ / 64, BS / 64, 4), dim3(256), 0, stream,
                       rs_h, rs_l, s2_h, s2_l, part4, BS, D_, D_);
    // 10. s2n-reduce + LN2 (fused) -> out
    hipLaunchKernelGGL(reduceln_kernel, dim3(BS), dim3(256), 0, stream,
                       part4, x, s2n_b, ln2_g, ln2_b, out);
}